// Round 6
// baseline (376.392 us; speedup 1.0000x reference)
//
#include <hip/hip_runtime.h>
#include <hip/hip_bf16.h>
#include <cstdint>

// B=2, HW=64 -> 128 rows of S=256; M = 32768. D=512, HEADS=8, DK=64,
// 3*H*DK=1536, KSIZE=7. Inputs/outputs fp32; internal compute bf16 MFMA.
//
// R6 structure: barrier-free GEMM K-loop. A lives in global in
// "fragment-stream" order per 64-row group: chunk slot = rr*64 + (c ^ (rr&7)),
// rr = row within group (0..63), c = 16B-chunk column (0..31 for K=512... c in
// 0..63 for 512 bf16 cols). GEMM blocks stage their whole 64x512 A-strip into
// LDS once (64 KB) via global_load_lds, then sweep n-groups with no further
// barriers. B is in R5's frag-shuffled order (coalesced 1KB/wave loads, L2-resident).

typedef __bf16 bf16x8 __attribute__((ext_vector_type(8)));
typedef float f32x4 __attribute__((ext_vector_type(4)));

__device__ __forceinline__ uint16_t f2bf(float f) {
    uint32_t u = __builtin_bit_cast(uint32_t, f);
    return (uint16_t)((u + 0x7fffu + ((u >> 16) & 1u)) >> 16);
}
__device__ __forceinline__ float bflo(uint32_t u) { return __builtin_bit_cast(float, u << 16); }
__device__ __forceinline__ float bfhi(uint32_t u) { return __builtin_bit_cast(float, u & 0xffff0000u); }

__device__ __forceinline__ void unpack8(uint4 v, float* f) {
    f[0] = bflo(v.x); f[1] = bfhi(v.x);
    f[2] = bflo(v.y); f[3] = bfhi(v.y);
    f[4] = bflo(v.z); f[5] = bfhi(v.z);
    f[6] = bflo(v.w); f[7] = bfhi(v.w);
}
__device__ __forceinline__ uint32_t pack2(float a, float b) {
    return (uint32_t)f2bf(a) | ((uint32_t)f2bf(b) << 16);
}

#define GLOAD_LDS16(gp, lp)                                                        \
    __builtin_amdgcn_global_load_lds((const __attribute__((address_space(1))) void*)(gp), \
                                     (__attribute__((address_space(3))) void*)(lp), 16, 0, 0)

// ---------------------------------------------------------------------------
// X fp32 [32768 x 512] -> A-fragment-stream bf16. Block = one 64-row group.
// LDS shuffle keeps global reads and writes fully coalesced.
// ---------------------------------------------------------------------------
__global__ __launch_bounds__(256)
void cvt_shuffle(const float* __restrict__ X, uint4* __restrict__ Afrag) {
    __shared__ uint4 lds[4096];  // 64 KB
    const int g64 = blockIdx.x;
    const int tid = threadIdx.x;
#pragma unroll
    for (int it = 0; it < 16; ++it) {
        int f  = it * 256 + tid;
        int rr = f >> 6;          // wave-uniform row
        int c  = f & 63;          // = lane
        const float4* s = (const float4*)(X + ((size_t)g64 * 64 + rr) * 512 + c * 8);
        float4 a = s[0], b = s[1];
        uint4 o;
        o.x = pack2(a.x, a.y);
        o.y = pack2(a.z, a.w);
        o.z = pack2(b.x, b.y);
        o.w = pack2(b.z, b.w);
        lds[rr * 64 + (c ^ (rr & 7))] = o;  // 8-way-balanced banks
    }
    __syncthreads();
#pragma unroll
    for (int it = 0; it < 16; ++it) {
        int i = it * 256 + tid;
        Afrag[(size_t)g64 * 4096 + i] = lds[i];
    }
}

// ---------------------------------------------------------------------------
// transpose + convert: out[c*R + r] = bf16(in[r*C + c])  (weights, one-time)
// ---------------------------------------------------------------------------
__global__ void transpose_cvt(const float* __restrict__ in, uint16_t* __restrict__ out,
                              int R, int C) {
    int idx = blockIdx.x * 256 + threadIdx.x;
    if (idx >= R * C) return;
    int r = idx / C;
    int c = idx - r * C;
    out[(size_t)c * R + r] = f2bf(in[idx]);
}

// ---------------------------------------------------------------------------
// BT[N][K] bf16 -> MFMA B-fragment order (R5, verified):
//   out[((g*(K/32)+kt)*4+nt)*64 + lane] = BT[g*64+nt*16+(lane&15)][kt*32+(lane>>4)*8 ..]
// ---------------------------------------------------------------------------
__global__ void frag_shuffle(const uint16_t* __restrict__ BT, uint4* __restrict__ out,
                             int N, int K) {
    int idx = blockIdx.x * 256 + threadIdx.x;
    int kt_n = K / 32;
    int total = (N / 64) * kt_n * 4 * 64;
    if (idx >= total) return;
    int lane = idx & 63;
    int nt   = (idx >> 6) & 3;
    int kt   = (idx >> 8) % kt_n;
    int g    = (idx >> 8) / kt_n;
    int row  = g * 64 + nt * 16 + (lane & 15);
    int col4 = kt * 4 + (lane >> 4);
    out[idx] = ((const uint4*)BT)[(size_t)row * (K / 8) + col4];
}

// ---------------------------------------------------------------------------
// Barrier-free strip GEMM: C[M,N] = A[M,512] @ B[512,N].
// Grid = M/64 blocks (one per 64-row A-strip; 512 blocks = 2/CU exactly).
// Stage A-strip (64 KB) into LDS once; each wave sweeps n-groups ng = wv,
// wv+4, ... independently: per kt, 4 coalesced B loads + 4 balanced ds_reads
// + 16 MFMA, no syncthreads -> compiler pipelines with vmcnt/lgkmcnt.
// ---------------------------------------------------------------------------
template <bool F32OUT>
__global__ __launch_bounds__(256, 2)
void gemm_strip(const uint4* __restrict__ Afrag, const uint4* __restrict__ Bfrag,
                void* __restrict__ Cout, int N) {
    __shared__ uint4 As[4096];  // 64 KB: slot = rr*64 + (c ^ (rr&7))

    const int tid  = threadIdx.x;
    const int lane = tid & 63;
    const int wv   = tid >> 6;
    const int r    = lane & 15;
    const int quad = lane >> 4;
    const int g64  = blockIdx.x;
    const int NG   = N >> 6;

    const uint4* src = Afrag + (size_t)g64 * 4096;
#pragma unroll
    for (int it = 0; it < 16; ++it) {
        int i = it * 256 + tid;
        GLOAD_LDS16(src + i, &As[i]);
    }
    __syncthreads();  // the only barrier

    // A ds_read slots per (kt, mt): rr = mt*16 + r, c = kt*4 + quad
    // slot = rr*64 + ((kt*4+quad) ^ (r&7))   [(mt*16+r)&7 == r&7]
    const int rx = r & 7;

    for (int ng = wv; ng < NG; ng += 4) {
        f32x4 acc[4][4];
#pragma unroll
        for (int i = 0; i < 4; ++i)
#pragma unroll
            for (int j = 0; j < 4; ++j) acc[i][j] = (f32x4){0.f, 0.f, 0.f, 0.f};

        const uint4* pBf = Bfrag + ((size_t)ng * 64) * 64 + lane;  // 16 kt * 4 nt = 64 chunks

#pragma unroll
        for (int kt = 0; kt < 16; ++kt) {
            bf16x8 bfr[4];
#pragma unroll
            for (int nt = 0; nt < 4; ++nt)
                bfr[nt] = *(const bf16x8*)&pBf[(kt * 4 + nt) * 64];
            bf16x8 af[4];
#pragma unroll
            for (int mt = 0; mt < 4; ++mt)
                af[mt] = *(const bf16x8*)&As[(mt * 16 + r) * 64 + ((kt * 4 + quad) ^ rx)];
#pragma unroll
            for (int mt = 0; mt < 4; ++mt)
#pragma unroll
                for (int nt = 0; nt < 4; ++nt)
                    acc[mt][nt] = __builtin_amdgcn_mfma_f32_16x16x32_bf16(af[mt], bfr[nt],
                                                                          acc[mt][nt], 0, 0, 0);
        }

        // D[row = quad*4 + i][col = lane&15]
#pragma unroll
        for (int mt = 0; mt < 4; ++mt) {
#pragma unroll
            for (int i = 0; i < 4; ++i) {
                long m = (long)g64 * 64 + mt * 16 + quad * 4 + i;
                if (F32OUT) {
                    float* crow = (float*)Cout + m * (long)N + ng * 64 + r;
#pragma unroll
                    for (int nt = 0; nt < 4; ++nt) crow[nt * 16] = acc[mt][nt][i];
                } else {
                    uint16_t* crow = (uint16_t*)Cout + m * (long)N + ng * 64 + r;
#pragma unroll
                    for (int nt = 0; nt < 4; ++nt) crow[nt * 16] = f2bf(acc[mt][nt][i]);
                }
            }
        }
    }
}

// ---------------------------------------------------------------------------
// Local window attention, LDS-staged K/V (R3 body). Output now written in
// A-fragment-stream order for GEMM2: chunk (row rr, colchunk c) at
// g64*4096 + rr*64 + (c ^ (rr&7)). Each thread fills one 128-B span.
// ---------------------------------------------------------------------------
__global__ __launch_bounds__(256, 2)
void local_attn(const uint16_t* __restrict__ qkv, const float* __restrict__ pb,
                uint4* __restrict__ attnf) {
    __shared__ uint4 smem[4096];  // [0,2048): K chunks, [2048,4096): V chunks

    const int h  = blockIdx.x & 7;
    const int bn = blockIdx.x >> 3;
    const int s  = threadIdx.x;
    const size_t base = (size_t)bn * 256 * 1536;

#pragma unroll
    for (int it = 0; it < 16; ++it) {
        int i   = threadIdx.x + it * 256;
        int a   = i >> 11;        // 0=K, 1=V
        int idx = i & 2047;
        int sp  = idx >> 3;
        int c8  = idx & 7;
        const uint16_t* src = qkv + base + (size_t)sp * 1536 + 512 + a * 512 + h * 64 + c8 * 8;
        smem[a * 2048 + sp * 8 + (c8 ^ (sp & 7))] = *(const uint4*)src;
    }

    const uint16_t* qrow = qkv + base + (size_t)s * 1536 + h * 64;
    uint4 qc[8];
#pragma unroll
    for (int c = 0; c < 8; ++c) qc[c] = *(const uint4*)(qrow + c * 8);

    __syncthreads();

    float sc[7];
#pragma unroll
    for (int w = 0; w < 7; ++w) sc[w] = 0.f;

#pragma unroll
    for (int c = 0; c < 8; ++c) {
        float qf[8];
        unpack8(qc[c], qf);
#pragma unroll
        for (int w = 0; w < 7; ++w) {
            int sp = s + w - 3;
            if ((unsigned)sp < 256u) {
                uint4 kc = smem[sp * 8 + (c ^ (sp & 7))];
                float kf[8];
                unpack8(kc, kf);
#pragma unroll
                for (int j = 0; j < 8; ++j) sc[w] += qf[j] * kf[j];
            }
        }
    }

    const float* pbr = pb + ((size_t)h * 256 + s) * 7;
    float mx = -1e30f;
#pragma unroll
    for (int w = 0; w < 7; ++w) {
        sc[w] = sc[w] * 0.125f + pbr[w];
        mx = fmaxf(mx, sc[w]);
    }
    float p[7], sum = 0.f;
#pragma unroll
    for (int w = 0; w < 7; ++w) {
        p[w] = __expf(sc[w] - mx);
        sum += p[w];
    }
    const float inv = 1.f / sum;
#pragma unroll
    for (int w = 0; w < 7; ++w) p[w] *= inv;

    uint4 ov[8];
#pragma unroll
    for (int c = 0; c < 8; ++c) {
        float o[8] = {0.f, 0.f, 0.f, 0.f, 0.f, 0.f, 0.f, 0.f};
#pragma unroll
        for (int w = 0; w < 7; ++w) {
            int sp = s + w - 3;
            if ((unsigned)sp < 256u) {
                uint4 vc = smem[2048 + sp * 8 + (c ^ (sp & 7))];
                float vf[8];
                unpack8(vc, vf);
#pragma unroll
                for (int j = 0; j < 8; ++j) o[j] += p[w] * vf[j];
            }
        }
        ov[c].x = pack2(o[0], o[1]);
        ov[c].y = pack2(o[2], o[3]);
        ov[c].z = pack2(o[4], o[5]);
        ov[c].w = pack2(o[6], o[7]);
    }

    // fragment-stream store: global row = bn*256+s -> g64 = row>>6, rr = s&63
    const int g64 = (bn << 2) + (s >> 6);
    const int rr  = s & 63;
    uint4* obase = attnf + (size_t)g64 * 4096 + rr * 64;
#pragma unroll
    for (int cc = 0; cc < 8; ++cc)
        obase[(h * 8 + cc) ^ (rr & 7)] = ov[cc];
}

// ---------------------------------------------------------------------------
extern "C" void kernel_launch(void* const* d_in, const int* in_sizes, int n_in,
                              void* d_out, int out_size, void* d_ws, size_t ws_size,
                              hipStream_t stream) {
    const float* X    = (const float*)d_in[0];  // 32768 x 512 fp32
    const float* pb   = (const float*)d_in[1];  // 8 x 256 x 7 fp32
    const float* Wqkv = (const float*)d_in[2];  // 512 x 1536 fp32
    const float* Wout = (const float*)d_in[3];  // 512 x 512 fp32
    float* out = (float*)d_out;                 // 32768 x 512 fp32

    char* ws = (char*)d_ws;
    uint16_t* WqkvT = (uint16_t*)(ws);              // 1536x512 bf16 = 1.5 MB
    uint16_t* WoutT = (uint16_t*)(ws + 1572864);    // 512x512  bf16 = 0.5 MB
    uint4*    BfQkv = (uint4*)(ws + 2097152);       // frag B, 1.5 MB
    uint4*    BfOut = (uint4*)(ws + 3670016);       // frag B, 0.5 MB
    uint16_t* qkvb  = (uint16_t*)(ws + 4194304);    // 32768x1536 bf16 = 96 MB (row-major)
    uint4*    Xfrag = (uint4*)(ws + 104857600);     // A-frag stream, 32 MB
    uint4*    attnf = Xfrag;  // alias: Xfrag dead after GEMM1 (stream-ordered)

    cvt_shuffle<<<512, 256, 0, stream>>>(X, Xfrag);
    transpose_cvt<<<(512 * 1536 + 255) / 256, 256, 0, stream>>>(Wqkv, WqkvT, 512, 1536);
    transpose_cvt<<<(512 * 512 + 255) / 256, 256, 0, stream>>>(Wout, WoutT, 512, 512);
    frag_shuffle<<<(1536 * 512 / 8 + 255) / 256, 256, 0, stream>>>(WqkvT, BfQkv, 1536, 512);
    frag_shuffle<<<(512 * 512 / 8 + 255) / 256, 256, 0, stream>>>(WoutT, BfOut, 512, 512);

    gemm_strip<false><<<512, 256, 0, stream>>>(Xfrag, BfQkv, qkvb, 1536);
    local_attn<<<1024, 256, 0, stream>>>(qkvb, pb, attnf);
    gemm_strip<true><<<512, 256, 0, stream>>>(attnf, BfOut, out, 512);
}